// Round 11
// baseline (889.472 us; speedup 1.0000x reference)
//
#include <hip/hip_runtime.h>

typedef short short8 __attribute__((ext_vector_type(8)));
typedef float f32x4 __attribute__((ext_vector_type(4)));
typedef unsigned short u16x4 __attribute__((ext_vector_type(4)));

// f32 -> bf16 bits (round-to-nearest-even; finite inputs only)
__device__ __forceinline__ unsigned short f2bf(float x){
  unsigned int u = __float_as_uint(x);
  u = u + 0x7FFFu + ((u >> 16) & 1u);
  return (unsigned short)(u >> 16);
}
__device__ __forceinline__ float bf2f(unsigned short h){
  return __uint_as_float(((unsigned int)h) << 16);
}
// truncation split: hi = trunc16(x), lo = RNE(x - hi). |err| <= 2^-17 |x|.
__device__ __forceinline__ void tsplit(float x, unsigned short& h, unsigned short& l){
  unsigned int u = __float_as_uint(x);
  h = (unsigned short)(u >> 16);
  l = f2bf(x - __uint_as_float(u & 0xFFFF0000u));
}

// ---------------------------------------------------------------- weight split conv
// Converts up to two f32 arrays into bf16 hi/lo planes (trunc split).
// Layer-stacked weights are contiguous -> 3 bulk dispatches convert ALL layers
// (round-10: 13 per-layer dispatches ~= 50 us of launch+work).
__global__ __launch_bounds__(256) void conv2(
    const float4* __restrict__ S0, int n0, u16x4* __restrict__ D0h, u16x4* __restrict__ D0l,
    const float4* __restrict__ S1, int n1, u16x4* __restrict__ D1h, u16x4* __restrict__ D1l)
{
  int i = blockIdx.x*256 + threadIdx.x;
  const float4* S; u16x4 *Dh, *Dl;
  if (i < n0){ S = S0 + i; Dh = D0h + i; Dl = D0l + i; }
  else { i -= n0; if (i >= n1) return; S = S1 + i; Dh = D1h + i; Dl = D1l + i; }
  float4 v = *S;
  float xs[4] = {v.x, v.y, v.z, v.w};
  u16x4 h, l;
  #pragma unroll
  for (int e = 0; e < 4; ++e){ unsigned short hh, ll; tsplit(xs[e], hh, ll); h[e]=hh; l[e]=ll; }
  *Dh = h; *Dl = l;
}

// ---------------------------------------------------------------- encoder stage 1
__global__ __launch_bounds__(256) void encoder_s1(
    const float* __restrict__ xc, const float* __restrict__ yc, const float* __restrict__ xt,
    const float* __restrict__ W1, const float* __restrict__ b1,
    float* __restrict__ hid)
{
  __shared__ float zin[10];
  int blk = blockIdx.x; int b = blk>>10; int t = blk & 1023;
  int tid = threadIdx.x;
  if (tid < 10){
    float v;
    if (tid < 8)      v = (t<512) ? xc[((size_t)b*512+t)*8+tid] : xt[((size_t)b*512+(t-512))*8+tid];
    else if (tid==8)  v = (t<512) ? yc[(size_t)b*512+t] : 0.f;
    else              v = (t<512) ? 0.f : 1.f;
    zin[tid]=v;
  }
  __syncthreads();
  float s = b1[tid];
  #pragma unroll
  for (int i=0;i<10;i++) s += zin[i]*W1[i*256+tid];
  hid[(size_t)blk*256 + tid] = fmaxf(s, 0.f);
}

// ---------------------------------------------------------------- layernorm v2 (fallback path only)
__global__ __launch_bounds__(256) void ln_v2(const float* __restrict__ z,
    const float* __restrict__ g, const float* __restrict__ be, float* __restrict__ h)
{
  const int row = blockIdx.x*4 + (threadIdx.x>>6);
  const int lane = threadIdx.x & 63;
  float4 x = *(const float4*)&z[(size_t)row*256 + lane*4];
  float s = (x.x+x.y)+(x.z+x.w);
  #pragma unroll
  for (int off=32; off; off>>=1) s += __shfl_xor(s, off);
  float mu = s * (1.f/256.f);
  float dx = x.x-mu, dy = x.y-mu, dz = x.z-mu, dw = x.w-mu;
  float v = (dx*dx+dy*dy)+(dz*dz+dw*dw);
  #pragma unroll
  for (int off=32; off; off>>=1) v += __shfl_xor(v, off);
  float r = rsqrtf(v*(1.f/256.f) + 1e-5f);
  float4 gv = *(const float4*)&g[lane*4];
  float4 bv = *(const float4*)&be[lane*4];
  float4 o;
  o.x = dx*r*gv.x + bv.x; o.y = dy*r*gv.y + bv.y;
  o.z = dz*r*gv.z + bv.z; o.w = dw*r*gv.w + bv.w;
  *(float4*)&h[(size_t)row*256 + lane*4] = o;
}

// ---------------------------------------------------------------- gemm_mfma v4
// out = EPI(LN?(A) @ B + bias). 128x128 block, 4 waves, split-bf16 MFMA.
// APRE: 0 = A f32 (trunc-split in kernel)  1 = A bf16 plane (2-term MFMA)
// BPRE: 0 = B f32 (split in kernel)        1 = B pre-split hi/lo planes (copy)
// LNA : 1 = apply per-row LayerNorm to A during staging (APRE==0 only).
//       Row stats via prologue: each A-staging thread owns one row half;
//       shfl_xor(1) combines the pair -> mu/rstd in regs; STAGE applies
//       (x-mu)*rstd*g[col]+b[col] before the bf16 split. Kills the separate
//       LN kernel (12 dispatches + 192 MB traffic).
// EPI : 0 plain f32 ; 1 relu f32 ; 2 +resid f32 ; 3 relu -> bf16 out
// Frag layouts HW-verified rounds 7-10. No launch_bounds min-waves (R4/R5).
template<int APRE, int BPRE, int EPI, int LNA>
__global__ __launch_bounds__(256) void gemm_mfma(
    const float* __restrict__ Af, const unsigned short* __restrict__ Ab,
    const float* __restrict__ Bf,
    const unsigned short* __restrict__ Bhg, const unsigned short* __restrict__ Blg,
    const float* __restrict__ lng, const float* __restrict__ lnb,
    const float* __restrict__ bias, const float* __restrict__ resid,
    float* __restrict__ outf, unsigned short* __restrict__ outb,
    int N, int K)
{
  constexpr int LDR = 40;
  __shared__ unsigned short Ah[128*LDR];
  __shared__ unsigned short Al[(APRE==0)?(128*LDR):8];
  __shared__ unsigned short Bh[128*LDR], Bl[128*LDR];

  const int tid = threadIdx.x;
  const int lane = tid & 63, wv = tid >> 6;
  const int wm0 = (wv >> 1) * 64, wn0 = (wv & 1) * 64;
  const int m0 = blockIdx.y * 128, n0 = blockIdx.x * 128;

  const int sar = tid >> 1, sak = (tid & 1) * 16;
  const int sbk = tid >> 3, sbn = (tid & 7) * 16;
  const int cA = ((sar >> 3) & 3) << 3;
  const int cB = ((sbn >> 4) & 3) << 3;

  const float* Apf = nullptr; const unsigned short* Apb = nullptr;
  if constexpr (APRE==0) Apf = Af + (size_t)(m0 + sar) * K + sak;
  else                   Apb = Ab + (size_t)(m0 + sar) * K + sak;
  const float* Bpf = nullptr; const unsigned short *Bph = nullptr, *Bpl = nullptr;
  if constexpr (BPRE==0) Bpf = Bf + (size_t)sbk * N + n0 + sbn;
  else { Bph = Bhg + (size_t)sbk * N + n0 + sbn; Bpl = Blg + (size_t)sbk * N + n0 + sbn; }

  const int rowb = lane & 15, kb = (lane >> 4) * 8;
  const int NT = K / 32;

  // ---- LN row stats (LNA): thread covers cols {t*32+sak .. +15} = half the row
  float mu = 0.f, rstd = 0.f;
  if constexpr (LNA==1){
    float s = 0.f, ss = 0.f;
    for (int t = 0; t < NT; ++t){
      #pragma unroll
      for (int g = 0; g < 4; ++g){
        float4 v = *(const float4*)&Apf[t*32 + g*4];
        s  += (v.x+v.y)+(v.z+v.w);
        ss += (v.x*v.x+v.y*v.y)+(v.z*v.z+v.w*v.w);
      }
    }
    s += __shfl_xor(s, 1); ss += __shfl_xor(ss, 1);
    mu = s * (1.f/256.f);
    rstd = rsqrtf(ss*(1.f/256.f) - mu*mu + 1e-5f);
  }

  f32x4 acc[4][4] = {};
  float4 pa[4], pb[4];
  u16x4 qa[4], qbh[4], qbl[4];

  auto LOADT = [&](int t){
    #pragma unroll
    for (int g = 0; g < 4; ++g){
      if constexpr (APRE==0) pa[g] = *(const float4*)&Apf[t*32 + g*4];
      else                   qa[g] = *(const u16x4*)&Apb[t*32 + g*4];
    }
    #pragma unroll
    for (int g = 0; g < 4; ++g){
      if constexpr (BPRE==0) pb[g] = *(const float4*)&Bpf[(size_t)t*32*N + g*4];
      else {
        qbh[g] = *(const u16x4*)&Bph[(size_t)t*32*N + g*4];
        qbl[g] = *(const u16x4*)&Bpl[(size_t)t*32*N + g*4];
      }
    }
  };
  auto STAGE = [&](int t){
    #pragma unroll
    for (int g = 0; g < 4; ++g){
      int idx = sar * LDR + ((sak + g * 4) ^ cA);
      if constexpr (APRE==0){
        float xs[4] = {pa[g].x, pa[g].y, pa[g].z, pa[g].w};
        if constexpr (LNA==1){
          float4 gv = *(const float4*)&lng[t*32 + sak + g*4];
          float4 bv = *(const float4*)&lnb[t*32 + sak + g*4];
          xs[0] = (xs[0]-mu)*rstd*gv.x + bv.x;
          xs[1] = (xs[1]-mu)*rstd*gv.y + bv.y;
          xs[2] = (xs[2]-mu)*rstd*gv.z + bv.z;
          xs[3] = (xs[3]-mu)*rstd*gv.w + bv.w;
        }
        u16x4 h, l;
        #pragma unroll
        for (int e = 0; e < 4; ++e){ unsigned short hh, ll; tsplit(xs[e], hh, ll); h[e]=hh; l[e]=ll; }
        *(u16x4*)&Ah[idx] = h; *(u16x4*)&Al[idx] = l;
      } else {
        *(u16x4*)&Ah[idx] = qa[g];
      }
    }
    int kx = sbk ^ cB;
    #pragma unroll
    for (int g = 0; g < 4; ++g){
      if constexpr (BPRE==0){
        float xs[4] = {pb[g].x, pb[g].y, pb[g].z, pb[g].w};
        #pragma unroll
        for (int e = 0; e < 4; ++e){
          int n = sbn + g * 4 + e;
          unsigned short hh, ll; tsplit(xs[e], hh, ll);
          Bh[n * LDR + kx] = hh; Bl[n * LDR + kx] = ll;
        }
      } else {
        #pragma unroll
        for (int e = 0; e < 4; ++e){
          int n = sbn + g * 4 + e;
          Bh[n * LDR + kx] = qbh[g][e]; Bl[n * LDR + kx] = qbl[g][e];
        }
      }
    }
  };

  LOADT(0);
  STAGE(0);
  __syncthreads();

  for (int t = 0; t < NT; ++t){
    if (t + 1 < NT) LOADT(t + 1);
    short8 bh[4], bl[4];
    #pragma unroll
    for (int ct = 0; ct < 4; ++ct){
      int n = wn0 + ct * 16 + rowb;
      int idx = n * LDR + (kb ^ (((n >> 4) & 3) << 3));
      bh[ct] = *(const short8*)&Bh[idx];
      bl[ct] = *(const short8*)&Bl[idx];
    }
    #pragma unroll
    for (int rt = 0; rt < 4; ++rt){
      int r = wm0 + rt * 16 + rowb;
      int idx = r * LDR + (kb ^ (((r >> 3) & 3) << 3));
      short8 ah = *(const short8*)&Ah[idx];
      #pragma unroll
      for (int ct = 0; ct < 4; ++ct){
        acc[rt][ct] = __builtin_amdgcn_mfma_f32_16x16x32_bf16(ah, bh[ct], acc[rt][ct], 0, 0, 0);
        acc[rt][ct] = __builtin_amdgcn_mfma_f32_16x16x32_bf16(ah, bl[ct], acc[rt][ct], 0, 0, 0);
      }
      if constexpr (APRE==0){
        short8 al = *(const short8*)&Al[idx];
        #pragma unroll
        for (int ct = 0; ct < 4; ++ct)
          acc[rt][ct] = __builtin_amdgcn_mfma_f32_16x16x32_bf16(al, bh[ct], acc[rt][ct], 0, 0, 0);
      }
    }
    if (t + 1 < NT){
      __syncthreads();
      STAGE(t + 1);
      __syncthreads();
    }
  }

  // epilogue: C/D layout col=lane&15, row=(lane>>4)*4+q
  #pragma unroll
  for (int ct = 0; ct < 4; ++ct){
    int gc = n0 + wn0 + ct * 16 + rowb;
    float bv = bias[gc];
    #pragma unroll
    for (int rt = 0; rt < 4; ++rt){
      int gr0 = m0 + wm0 + rt * 16 + (lane >> 4) * 4;
      #pragma unroll
      for (int q = 0; q < 4; ++q){
        size_t off = (size_t)(gr0 + q) * N + gc;
        float v = acc[rt][ct][q] + bv;
        if constexpr (EPI == 1) v = fmaxf(v, 0.f);
        if constexpr (EPI == 2) v += resid[off];
        if constexpr (EPI == 3) outb[off] = f2bf(fmaxf(v, 0.f));
        else                    outf[off] = v;
      }
    }
  }
}

// ---------------------------------------------------------------- attention v6 (MFMA flash)
// (unchanged — verified rounds 8-10) 1024-thread blocks, 16 waves.
__global__ __launch_bounds__(1024) void attn_v6(
    const float* __restrict__ qkv, float* __restrict__ o)
{
  constexpr int LDK = 40;
  constexpr int LDV = 520;
  __shared__ unsigned short Khi[512*LDK];
  __shared__ unsigned short Klo[512*LDK];
  __shared__ unsigned short Vt[32*LDV];
  __shared__ float cbuf[16][16];

  const int tid = threadIdx.x;
  const int qc = blockIdx.x, h = blockIdx.y, b = blockIdx.z;
  const float* base = qkv + (size_t)b*1024*768;
  const int hoff = h*32;
  const float sc = 0.17677669529663687f;

  #pragma unroll
  for (int t = 0; t < 4; ++t){
    int i = tid + t*1024;
    int row = i >> 3, c4 = (i & 7) * 4;
    float4 kv = *(const float4*)&base[(size_t)row*768 + 256 + hoff + c4];
    float ks[4] = {kv.x, kv.y, kv.z, kv.w};
    u16x4 hk, lk;
    #pragma unroll
    for (int e = 0; e < 4; ++e){
      unsigned short hb_ = f2bf(ks[e]);
      hk[e] = hb_; lk[e] = f2bf(ks[e] - bf2f(hb_));
    }
    *(u16x4*)&Khi[row*LDK + c4] = hk;
    *(u16x4*)&Klo[row*LDK + c4] = lk;
    float4 vv = *(const float4*)&base[(size_t)row*768 + 512 + hoff + c4];
    float vs[4] = {vv.x, vv.y, vv.z, vv.w};
    #pragma unroll
    for (int e = 0; e < 4; ++e)
      Vt[(c4 + e)*LDV + row] = f2bf(vs[e]);
  }

  const int wv = tid >> 6, lane = tid & 63;
  const int g = lane >> 4, r = lane & 15;
  const int q0w = qc*256 + wv*16;

  short8 qh, ql;
  {
    const float* qp = &base[(size_t)(q0w + r)*768 + hoff + g*8];
    float4 a = *(const float4*)qp;
    float4 c = *(const float4*)(qp + 4);
    float xs[8] = {a.x*sc, a.y*sc, a.z*sc, a.w*sc, c.x*sc, c.y*sc, c.z*sc, c.w*sc};
    #pragma unroll
    for (int e = 0; e < 8; ++e){
      unsigned short hb_ = f2bf(xs[e]);
      qh[e] = (short)hb_;
      ql[e] = (short)f2bf(xs[e] - bf2f(hb_));
    }
  }
  __syncthreads();

  float m = -1e30f, l = 0.f;
  f32x4 O0 = {0.f,0.f,0.f,0.f}, O1 = {0.f,0.f,0.f,0.f};

  for (int st = 0; st < 16; ++st){
    int key0 = st*32 + (r >> 2)*8 + (r & 3);
    short8 ah0 = *(const short8*)&Khi[key0*LDK + g*8];
    short8 al0 = *(const short8*)&Klo[key0*LDK + g*8];
    short8 ah1 = *(const short8*)&Khi[(key0+4)*LDK + g*8];
    short8 al1 = *(const short8*)&Klo[(key0+4)*LDK + g*8];
    f32x4 s0 = {0.f,0.f,0.f,0.f}, s1 = {0.f,0.f,0.f,0.f};
    s0 = __builtin_amdgcn_mfma_f32_16x16x32_bf16(ah0, qh, s0, 0,0,0);
    s0 = __builtin_amdgcn_mfma_f32_16x16x32_bf16(ah0, ql, s0, 0,0,0);
    s0 = __builtin_amdgcn_mfma_f32_16x16x32_bf16(al0, qh, s0, 0,0,0);
    s1 = __builtin_amdgcn_mfma_f32_16x16x32_bf16(ah1, qh, s1, 0,0,0);
    s1 = __builtin_amdgcn_mfma_f32_16x16x32_bf16(ah1, ql, s1, 0,0,0);
    s1 = __builtin_amdgcn_mfma_f32_16x16x32_bf16(al1, qh, s1, 0,0,0);
    float pv[8] = {s0[0],s0[1],s0[2],s0[3], s1[0],s1[1],s1[2],s1[3]};
    float tm = pv[0];
    #pragma unroll
    for (int j = 1; j < 8; ++j) tm = fmaxf(tm, pv[j]);
    tm = fmaxf(tm, __shfl_xor(tm, 16));
    tm = fmaxf(tm, __shfl_xor(tm, 32));
    float mn = fmaxf(m, tm);
    float ts = 0.f;
    #pragma unroll
    for (int j = 0; j < 8; ++j){ pv[j] = __expf(pv[j] - mn); ts += pv[j]; }
    ts += __shfl_xor(ts, 16);
    ts += __shfl_xor(ts, 32);
    if (__any(mn > m)){
      float corr = __expf(m - mn);
      if (lane < 16) cbuf[wv][lane] = corr;
      asm volatile("s_waitcnt lgkmcnt(0)" ::: "memory");
      f32x4 cf = *(const f32x4*)&cbuf[wv][g*4];
      #pragma unroll
      for (int j = 0; j < 4; ++j){ O0[j] *= cf[j]; O1[j] *= cf[j]; }
      l *= corr;
      m = mn;
    }
    l += ts;
    short8 pa;
    #pragma unroll
    for (int j = 0; j < 8; ++j) pa[j] = (short)f2bf(pv[j]);
    short8 v0 = *(const short8*)&Vt[(size_t)r*LDV + st*32 + g*8];
    short8 v1 = *(const short8*)&Vt[(size_t)(r+16)*LDV + st*32 + g*8];
    O0 = __builtin_amdgcn_mfma_f32_16x16x32_bf16(pa, v0, O0, 0,0,0);
    O1 = __builtin_amdgcn_mfma_f32_16x16x32_bf16(pa, v1, O1, 0,0,0);
  }

  if (qc >= 2){
    const float* kp = &base[(size_t)(q0w + r)*768 + 256 + hoff + g*8];
    float4 a = *(const float4*)kp;
    float4 c = *(const float4*)(kp + 4);
    float xs[8] = {a.x, a.y, a.z, a.w, c.x, c.y, c.z, c.w};
    short8 ah, al;
    #pragma unroll
    for (int e = 0; e < 8; ++e){
      unsigned short hb_ = f2bf(xs[e]);
      ah[e] = (short)hb_;
      al[e] = (short)f2bf(xs[e] - bf2f(hb_));
    }
    f32x4 s = {0.f,0.f,0.f,0.f};
    s = __builtin_amdgcn_mfma_f32_16x16x32_bf16(ah, qh, s, 0,0,0);
    s = __builtin_amdgcn_mfma_f32_16x16x32_bf16(ah, ql, s, 0,0,0);
    s = __builtin_amdgcn_mfma_f32_16x16x32_bf16(al, qh, s, 0,0,0);
    float pv[8] = {0.f,0.f,0.f,0.f,0.f,0.f,0.f,0.f};
    float tm = -1e30f;
    #pragma unroll
    for (int j = 0; j < 4; ++j){
      bool al_ = (g*4 + j) == r;
      tm = fmaxf(tm, al_ ? s[j] : -1e30f);
    }
    tm = fmaxf(tm, __shfl_xor(tm, 16));
    tm = fmaxf(tm, __shfl_xor(tm, 32));
    float mn = fmaxf(m, tm);
    float ts = 0.f;
    #pragma unroll
    for (int j = 0; j < 4; ++j){
      bool al_ = (g*4 + j) == r;
      pv[j] = al_ ? __expf(s[j] - mn) : 0.f;
      ts += pv[j];
    }
    ts += __shfl_xor(ts, 16);
    ts += __shfl_xor(ts, 32);
    if (__any(mn > m)){
      float corr = __expf(m - mn);
      if (lane < 16) cbuf[wv][lane] = corr;
      asm volatile("s_waitcnt lgkmcnt(0)" ::: "memory");
      f32x4 cf = *(const f32x4*)&cbuf[wv][g*4];
      #pragma unroll
      for (int j = 0; j < 4; ++j){ O0[j] *= cf[j]; O1[j] *= cf[j]; }
      l *= corr;
      m = mn;
    }
    l += ts;
    short8 pa, v0, v1;
    #pragma unroll
    for (int j = 0; j < 8; ++j) pa[j] = (short)f2bf(pv[j]);
    #pragma unroll
    for (int j = 0; j < 4; ++j){
      const float* vp = &base[(size_t)(q0w + g*4 + j)*768 + 512 + hoff];
      v0[j] = (short)f2bf(vp[r]);
      v1[j] = (short)f2bf(vp[r + 16]);
      v0[j+4] = 0; v1[j+4] = 0;
    }
    O0 = __builtin_amdgcn_mfma_f32_16x16x32_bf16(pa, v0, O0, 0,0,0);
    O1 = __builtin_amdgcn_mfma_f32_16x16x32_bf16(pa, v1, O1, 0,0,0);
  }

  float inv = 1.f / l;
  if (lane < 16) cbuf[wv][lane] = inv;
  asm volatile("s_waitcnt lgkmcnt(0)" ::: "memory");
  f32x4 iv = *(const f32x4*)&cbuf[wv][g*4];
  float* op = o + ((size_t)b*1024 + q0w + g*4)*256 + hoff;
  #pragma unroll
  for (int j = 0; j < 4; ++j){
    op[(size_t)j*256 + r]      = O0[j] * iv[j];
    op[(size_t)j*256 + r + 16] = O1[j] * iv[j];
  }
}

// ---------------------------------------------------------------- launch
extern "C" void kernel_launch(void* const* d_in, const int* in_sizes, int n_in,
                              void* d_out, int out_size, void* d_ws, size_t ws_size,
                              hipStream_t stream)
{
  (void)in_sizes; (void)n_in; (void)out_size;
  const float* xc   = (const float*)d_in[0];
  const float* yc   = (const float*)d_in[1];
  const float* xt   = (const float*)d_in[2];
  const float* eW1  = (const float*)d_in[3];
  const float* eb1  = (const float*)d_in[4];
  const float* eW2  = (const float*)d_in[5];
  const float* eb2  = (const float*)d_in[6];
  const float* Wqkv = (const float*)d_in[7];
  const float* bqkv = (const float*)d_in[8];
  const float* Wo   = (const float*)d_in[9];
  const float* bo   = (const float*)d_in[10];
  const float* ln1g = (const float*)d_in[11];
  const float* ln1b = (const float*)d_in[12];
  const float* ln2g = (const float*)d_in[13];
  const float* ln2b = (const float*)d_in[14];
  const float* Wff1 = (const float*)d_in[15];
  const float* bff1 = (const float*)d_in[16];
  const float* Wff2 = (const float*)d_in[17];
  const float* bff2 = (const float*)d_in[18];

  float* zf = (float*)d_out;            // residual stream [8][1024][256] f32 = 8 MB
  char* ws = (char*)d_ws;
  float* hb      = (float*)(ws);                        // 8 MiB (attn out / enc hid)
  float* scratch = (float*)(ws + (size_t)8*1024*1024);  // qkv f32 (24 MiB) / ffh bf16 (16 MiB)

  const size_t MiB = 1024*1024;
  const bool hugews = (ws_size == 0) || (ws_size >= 64*MiB);   // fill counters show ws = 256 MiB
  const bool bigws  = (ws_size == 0) || (ws_size >= 33*MiB);

  if (hugews){
    // persistent split planes at ws+32MiB (18.25 MiB; hb 8 + qkv 24 + this = 50.3 < 64):
    unsigned short* W = (unsigned short*)(ws + 32*MiB);
    unsigned short* qkvh_a = W;                 // 6*196608
    unsigned short* qkvl_a = W + 1179648;
    unsigned short* woh_a  = W + 2359296;       // 6*65536
    unsigned short* wol_a  = W + 2752512;
    unsigned short* w1h_a  = W + 3145728;       // 6*262144
    unsigned short* w1l_a  = W + 4718592;
    unsigned short* w2h_a  = W + 6291456;
    unsigned short* w2l_a  = W + 7864320;
    unsigned short* e2h    = W + 9437184;       // 65536
    unsigned short* e2l    = W + 9502720;
    unsigned short* ffh_b  = (unsigned short*)scratch;   // 16 MiB, after attn

    // bulk weight conversion: 3 dispatches for all layers
    conv2<<<1536, 256, 0, stream>>>((const float4*)Wqkv, 294912, (u16x4*)qkvh_a, (u16x4*)qkvl_a,
                                    (const float4*)Wo,    98304, (u16x4*)woh_a,  (u16x4*)wol_a);
    conv2<<<3072, 256, 0, stream>>>((const float4*)Wff1, 393216, (u16x4*)w1h_a, (u16x4*)w1l_a,
                                    (const float4*)Wff2, 393216, (u16x4*)w2h_a, (u16x4*)w2l_a);
    conv2<<<64, 256, 0, stream>>>((const float4*)eW2, 16384, (u16x4*)e2h, (u16x4*)e2l,
                                  nullptr, 0, nullptr, nullptr);

    encoder_s1<<<8192, 256, 0, stream>>>(xc, yc, xt, eW1, eb1, hb);
    gemm_mfma<0,1,0,0><<<dim3(2,64), 256, 0, stream>>>(hb, nullptr, nullptr, e2h, e2l,
                                                       nullptr, nullptr, eb2, nullptr, zf, nullptr, 256, 256);

    for (int l=0; l<6; l++){
      unsigned short* qkvh = qkvh_a + (size_t)l*196608;
      unsigned short* qkvl = qkvl_a + (size_t)l*196608;
      unsigned short* woh  = woh_a  + (size_t)l*65536;
      unsigned short* wol  = wol_a  + (size_t)l*65536;
      unsigned short* w1h  = w1h_a  + (size_t)l*262144;
      unsigned short* w1l  = w1l_a  + (size_t)l*262144;
      unsigned short* w2h  = w2h_a  + (size_t)l*262144;
      unsigned short* w2l  = w2l_a  + (size_t)l*262144;

      // qkv = LN1(z) @ Wq  (LN fused into A-staging)
      gemm_mfma<0,1,0,1><<<dim3(6,64), 256, 0, stream>>>(zf, nullptr, nullptr, qkvh, qkvl,
                                                         ln1g+l*256, ln1b+l*256,
                                                         bqkv+l*768, nullptr, scratch, nullptr, 768, 256);
      attn_v6<<<dim3(4,8,8), 1024, 0, stream>>>(scratch, hb);
      gemm_mfma<0,1,2,0><<<dim3(2,64), 256, 0, stream>>>(hb, nullptr, nullptr, woh, wol,
                                                         nullptr, nullptr, bo+l*256, zf, zf, nullptr, 256, 256);
      // ffh = relu(LN2(z) @ W1) -> bf16 (LN fused; qkv scratch dead -> ffh overlays it)
      gemm_mfma<0,1,3,1><<<dim3(8,64), 256, 0, stream>>>(zf, nullptr, nullptr, w1h, w1l,
                                                         ln2g+l*256, ln2b+l*256,
                                                         bff1+l*1024, nullptr, nullptr, ffh_b, 1024, 256);
      gemm_mfma<1,1,2,0><<<dim3(2,64), 256, 0, stream>>>(nullptr, ffh_b, nullptr, w2h, w2l,
                                                         nullptr, nullptr, bff2+l*256, zf, zf, nullptr, 256, 1024);
    }
  } else if (bigws){
    // round-10 layout: per-layer conv into wsA/wsB + LN-fused gemms
    unsigned short* wsA = (unsigned short*)(ws + 32*MiB);
    unsigned short* wsB = (unsigned short*)(ws + 24*MiB);
    unsigned short* qkvh = wsA,            * qkvl = wsA + 196608;
    unsigned short* woh  = wsA + 393216,   * wol  = wsA + 458752;
    unsigned short* w1h  = wsB,            * w1l  = wsB + 262144;
    unsigned short* w2h  = wsB + 524288,   * w2l  = wsB + 786432;
    unsigned short* ffh_b = (unsigned short*)scratch;

    conv2<<<64, 256, 0, stream>>>((const float4*)eW2, 16384, (u16x4*)wsA, (u16x4*)(wsA+65536),
                                  nullptr, 0, nullptr, nullptr);
    encoder_s1<<<8192, 256, 0, stream>>>(xc, yc, xt, eW1, eb1, hb);
    gemm_mfma<0,1,0,0><<<dim3(2,64), 256, 0, stream>>>(hb, nullptr, nullptr, wsA, wsA+65536,
                                                       nullptr, nullptr, eb2, nullptr, zf, nullptr, 256, 256);
    for (int l=0; l<6; l++){
      const float* Wq = Wqkv + (size_t)l*256*768;
      const float* Wl = Wo   + (size_t)l*256*256;
      const float* W1 = Wff1 + (size_t)l*256*1024;
      const float* W2 = Wff2 + (size_t)l*1024*256;

      conv2<<<256, 256, 0, stream>>>((const float4*)Wq, 49152, (u16x4*)qkvh, (u16x4*)qkvl,
                                     (const float4*)Wl, 16384, (u16x4*)woh,  (u16x4*)wol);
      gemm_mfma<0,1,0,1><<<dim3(6,64), 256, 0, stream>>>(zf, nullptr, nullptr, qkvh, qkvl,
                                                         ln1g+l*256, ln1b+l*256,
                                                         bqkv+l*768, nullptr, scratch, nullptr, 768, 256);
      attn_v6<<<dim3(4,8,8), 1024, 0, stream>>>(scratch, hb);
      conv2<<<512, 256, 0, stream>>>((const float4*)W1, 65536, (u16x4*)w1h, (u16x4*)w1l,
                                     (const float4*)W2, 65536, (u16x4*)w2h, (u16x4*)w2l);
      gemm_mfma<0,1,2,0><<<dim3(2,64), 256, 0, stream>>>(hb, nullptr, nullptr, woh, wol,
                                                         nullptr, nullptr, bo+l*256, zf, zf, nullptr, 256, 256);
      gemm_mfma<0,1,3,1><<<dim3(8,64), 256, 0, stream>>>(zf, nullptr, nullptr, w1h, w1l,
                                                         ln2g+l*256, ln2b+l*256,
                                                         bff1+l*1024, nullptr, nullptr, ffh_b, 1024, 256);
      gemm_mfma<1,1,2,0><<<dim3(2,64), 256, 0, stream>>>(nullptr, ffh_b, nullptr, w2h, w2l,
                                                         nullptr, nullptr, bff2+l*256, zf, zf, nullptr, 256, 1024);
    }
  } else {
    // minimal-ws fallback: in-kernel conversion + separate LN, chunked scratch
    encoder_s1<<<8192, 256, 0, stream>>>(xc, yc, xt, eW1, eb1, hb);
    gemm_mfma<0,0,0,0><<<dim3(2,64), 256, 0, stream>>>(hb, nullptr, eW2, nullptr, nullptr,
                                                       nullptr, nullptr, eb2, nullptr, zf, nullptr, 256, 256);
    for (int l=0; l<6; l++){
      const float* Wq = Wqkv + (size_t)l*256*768;
      const float* Wl = Wo   + (size_t)l*256*256;
      const float* W1 = Wff1 + (size_t)l*256*1024;
      const float* W2 = Wff2 + (size_t)l*1024*256;

      ln_v2<<<2048, 256, 0, stream>>>(zf, ln1g+l*256, ln1b+l*256, hb);
      for (int c=0; c<4; c++){
        float* hrows = hb + (size_t)c*2048*256;
        gemm_mfma<0,0,0,0><<<dim3(6,16), 256, 0, stream>>>(hrows, nullptr, Wq, nullptr, nullptr,
                                                           nullptr, nullptr, bqkv+l*768, nullptr, scratch, nullptr, 768, 256);
        attn_v6<<<dim3(4,8,2), 1024, 0, stream>>>(scratch, hrows);
      }
      gemm_mfma<0,0,2,0><<<dim3(2,64), 256, 0, stream>>>(hb, nullptr, Wl, nullptr, nullptr,
                                                         nullptr, nullptr, bo+l*256, zf, zf, nullptr, 256, 256);
      ln_v2<<<2048, 256, 0, stream>>>(zf, ln2g+l*256, ln2b+l*256, hb);
      for (int c=0; c<4; c++){
        float* hrows = hb + (size_t)c*2048*256;
        float* zrows = zf + (size_t)c*2048*256;
        gemm_mfma<0,0,1,0><<<dim3(8,16), 256, 0, stream>>>(hrows, nullptr, W1, nullptr, nullptr,
                                                           nullptr, nullptr, bff1+l*1024, nullptr, scratch, nullptr, 1024, 256);
        gemm_mfma<0,0,2,0><<<dim3(2,16), 256, 0, stream>>>(scratch, nullptr, W2, nullptr, nullptr,
                                                           nullptr, nullptr, bff2+l*256, zrows, zrows, nullptr, 256, 1024);
      }
    }
  }
}

// Round 12
// 863.064 us; speedup vs baseline: 1.0306x; 1.0306x over previous
//
#include <hip/hip_runtime.h>

typedef short short8 __attribute__((ext_vector_type(8)));
typedef float f32x4 __attribute__((ext_vector_type(4)));
typedef unsigned short u16x4 __attribute__((ext_vector_type(4)));

// f32 -> bf16 bits (round-to-nearest-even; finite inputs only)
__device__ __forceinline__ unsigned short f2bf(float x){
  unsigned int u = __float_as_uint(x);
  u = u + 0x7FFFu + ((u >> 16) & 1u);
  return (unsigned short)(u >> 16);
}
__device__ __forceinline__ float bf2f(unsigned short h){
  return __uint_as_float(((unsigned int)h) << 16);
}
// truncation split: hi = trunc16(x), lo = RNE(x - hi). |err| <= 2^-17 |x|.
__device__ __forceinline__ void tsplit(float x, unsigned short& h, unsigned short& l){
  unsigned int u = __float_as_uint(x);
  h = (unsigned short)(u >> 16);
  l = f2bf(x - __uint_as_float(u & 0xFFFF0000u));
}

// ---------------------------------------------------------------- weight split conv
__global__ __launch_bounds__(256) void conv2(
    const float4* __restrict__ S0, int n0, u16x4* __restrict__ D0h, u16x4* __restrict__ D0l,
    const float4* __restrict__ S1, int n1, u16x4* __restrict__ D1h, u16x4* __restrict__ D1l)
{
  int i = blockIdx.x*256 + threadIdx.x;
  const float4* S; u16x4 *Dh, *Dl;
  if (i < n0){ S = S0 + i; Dh = D0h + i; Dl = D0l + i; }
  else { i -= n0; if (i >= n1) return; S = S1 + i; Dh = D1h + i; Dl = D1l + i; }
  float4 v = *S;
  float xs[4] = {v.x, v.y, v.z, v.w};
  u16x4 h, l;
  #pragma unroll
  for (int e = 0; e < 4; ++e){ unsigned short hh, ll; tsplit(xs[e], hh, ll); h[e]=hh; l[e]=ll; }
  *Dh = h; *Dl = l;
}

// ---------------------------------------------------------------- encoder stage 1
__global__ __launch_bounds__(256) void encoder_s1(
    const float* __restrict__ xc, const float* __restrict__ yc, const float* __restrict__ xt,
    const float* __restrict__ W1, const float* __restrict__ b1,
    float* __restrict__ hid)
{
  __shared__ float zin[10];
  int blk = blockIdx.x; int b = blk>>10; int t = blk & 1023;
  int tid = threadIdx.x;
  if (tid < 10){
    float v;
    if (tid < 8)      v = (t<512) ? xc[((size_t)b*512+t)*8+tid] : xt[((size_t)b*512+(t-512))*8+tid];
    else if (tid==8)  v = (t<512) ? yc[(size_t)b*512+t] : 0.f;
    else              v = (t<512) ? 0.f : 1.f;
    zin[tid]=v;
  }
  __syncthreads();
  float s = b1[tid];
  #pragma unroll
  for (int i=0;i<10;i++) s += zin[i]*W1[i*256+tid];
  hid[(size_t)blk*256 + tid] = fmaxf(s, 0.f);
}

// ---------------------------------------------------------------- LN stats (mu, rstd per row)
// Round-11 lesson: in-GEMM stats scan is recomputed per N-block (6-8x redundant
// z reads, ~100us aggregate). Stats once here (8MB read, 64KB write -- no 8MB
// LN-output write like ln_v2); the GEMM applies LN during A-staging.
__global__ __launch_bounds__(256) void ln_stats(const float* __restrict__ z,
    float2* __restrict__ st)
{
  const int row = blockIdx.x*4 + (threadIdx.x>>6);
  const int lane = threadIdx.x & 63;
  float4 x = *(const float4*)&z[(size_t)row*256 + lane*4];
  float s  = (x.x+x.y)+(x.z+x.w);
  float ss = (x.x*x.x+x.y*x.y)+(x.z*x.z+x.w*x.w);
  #pragma unroll
  for (int off=32; off; off>>=1){ s += __shfl_xor(s, off); ss += __shfl_xor(ss, off); }
  if (lane == 0){
    float mu = s * (1.f/256.f);
    float rstd = rsqrtf(ss*(1.f/256.f) - mu*mu + 1e-5f);
    st[row] = make_float2(mu, rstd);
  }
}

// ---------------------------------------------------------------- layernorm v2 (fallback path only)
__global__ __launch_bounds__(256) void ln_v2(const float* __restrict__ z,
    const float* __restrict__ g, const float* __restrict__ be, float* __restrict__ h)
{
  const int row = blockIdx.x*4 + (threadIdx.x>>6);
  const int lane = threadIdx.x & 63;
  float4 x = *(const float4*)&z[(size_t)row*256 + lane*4];
  float s = (x.x+x.y)+(x.z+x.w);
  #pragma unroll
  for (int off=32; off; off>>=1) s += __shfl_xor(s, off);
  float mu = s * (1.f/256.f);
  float dx = x.x-mu, dy = x.y-mu, dz = x.z-mu, dw = x.w-mu;
  float v = (dx*dx+dy*dy)+(dz*dz+dw*dw);
  #pragma unroll
  for (int off=32; off; off>>=1) v += __shfl_xor(v, off);
  float r = rsqrtf(v*(1.f/256.f) + 1e-5f);
  float4 gv = *(const float4*)&g[lane*4];
  float4 bv = *(const float4*)&be[lane*4];
  float4 o;
  o.x = dx*r*gv.x + bv.x; o.y = dy*r*gv.y + bv.y;
  o.z = dz*r*gv.z + bv.z; o.w = dw*r*gv.w + bv.w;
  *(float4*)&h[(size_t)row*256 + lane*4] = o;
}

// ---------------------------------------------------------------- gemm_mfma v5
// out = EPI(LN?(A) @ B + bias). 128x128 block, 4 waves, split-bf16 MFMA.
// APRE: 0 = A f32 (trunc-split in kernel)  1 = A bf16 plane (2-term MFMA)
// BPRE: 0 = B f32 (split in kernel)        1 = B pre-split hi/lo planes (copy)
// LNA : 1 = apply LN to A during staging using PRECOMPUTED per-row stats
//       (one float2 read per thread -- no per-N-block scan, round-11 lesson).
// EPI : 0 plain f32 ; 1 relu f32 ; 2 +resid f32 ; 3 relu -> bf16 out
// Frag layouts HW-verified rounds 7-10. No launch_bounds min-waves (R4/R5).
template<int APRE, int BPRE, int EPI, int LNA>
__global__ __launch_bounds__(256) void gemm_mfma(
    const float* __restrict__ Af, const unsigned short* __restrict__ Ab,
    const float* __restrict__ Bf,
    const unsigned short* __restrict__ Bhg, const unsigned short* __restrict__ Blg,
    const float2* __restrict__ lnst,
    const float* __restrict__ lng, const float* __restrict__ lnb,
    const float* __restrict__ bias, const float* __restrict__ resid,
    float* __restrict__ outf, unsigned short* __restrict__ outb,
    int N, int K)
{
  constexpr int LDR = 40;
  __shared__ unsigned short Ah[128*LDR];
  __shared__ unsigned short Al[(APRE==0)?(128*LDR):8];
  __shared__ unsigned short Bh[128*LDR], Bl[128*LDR];

  const int tid = threadIdx.x;
  const int lane = tid & 63, wv = tid >> 6;
  const int wm0 = (wv >> 1) * 64, wn0 = (wv & 1) * 64;
  const int m0 = blockIdx.y * 128, n0 = blockIdx.x * 128;

  const int sar = tid >> 1, sak = (tid & 1) * 16;
  const int sbk = tid >> 3, sbn = (tid & 7) * 16;
  const int cA = ((sar >> 3) & 3) << 3;
  const int cB = ((sbn >> 4) & 3) << 3;

  const float* Apf = nullptr; const unsigned short* Apb = nullptr;
  if constexpr (APRE==0) Apf = Af + (size_t)(m0 + sar) * K + sak;
  else                   Apb = Ab + (size_t)(m0 + sar) * K + sak;
  const float* Bpf = nullptr; const unsigned short *Bph = nullptr, *Bpl = nullptr;
  if constexpr (BPRE==0) Bpf = Bf + (size_t)sbk * N + n0 + sbn;
  else { Bph = Bhg + (size_t)sbk * N + n0 + sbn; Bpl = Blg + (size_t)sbk * N + n0 + sbn; }

  const int rowb = lane & 15, kb = (lane >> 4) * 8;
  const int NT = K / 32;

  float mu = 0.f, rstd = 1.f;
  if constexpr (LNA==1){
    float2 st = lnst[m0 + sar];
    mu = st.x; rstd = st.y;
  }

  f32x4 acc[4][4] = {};
  float4 pa[4], pb[4];
  u16x4 qa[4], qbh[4], qbl[4];

  auto LOADT = [&](int t){
    #pragma unroll
    for (int g = 0; g < 4; ++g){
      if constexpr (APRE==0) pa[g] = *(const float4*)&Apf[t*32 + g*4];
      else                   qa[g] = *(const u16x4*)&Apb[t*32 + g*4];
    }
    #pragma unroll
    for (int g = 0; g < 4; ++g){
      if constexpr (BPRE==0) pb[g] = *(const float4*)&Bpf[(size_t)t*32*N + g*4];
      else {
        qbh[g] = *(const u16x4*)&Bph[(size_t)t*32*N + g*4];
        qbl[g] = *(const u16x4*)&Bpl[(size_t)t*32*N + g*4];
      }
    }
  };
  auto STAGE = [&](int t){
    #pragma unroll
    for (int g = 0; g < 4; ++g){
      int idx = sar * LDR + ((sak + g * 4) ^ cA);
      if constexpr (APRE==0){
        float xs[4] = {pa[g].x, pa[g].y, pa[g].z, pa[g].w};
        if constexpr (LNA==1){
          float4 gv = *(const float4*)&lng[t*32 + sak + g*4];
          float4 bv = *(const float4*)&lnb[t*32 + sak + g*4];
          xs[0] = (xs[0]-mu)*rstd*gv.x + bv.x;
          xs[1] = (xs[1]-mu)*rstd*gv.y + bv.y;
          xs[2] = (xs[2]-mu)*rstd*gv.z + bv.z;
          xs[3] = (xs[3]-mu)*rstd*gv.w + bv.w;
        }
        u16x4 h, l;
        #pragma unroll
        for (int e = 0; e < 4; ++e){ unsigned short hh, ll; tsplit(xs[e], hh, ll); h[e]=hh; l[e]=ll; }
        *(u16x4*)&Ah[idx] = h; *(u16x4*)&Al[idx] = l;
      } else {
        *(u16x4*)&Ah[idx] = qa[g];
      }
    }
    int kx = sbk ^ cB;
    #pragma unroll
    for (int g = 0; g < 4; ++g){
      if constexpr (BPRE==0){
        float xs[4] = {pb[g].x, pb[g].y, pb[g].z, pb[g].w};
        #pragma unroll
        for (int e = 0; e < 4; ++e){
          int n = sbn + g * 4 + e;
          unsigned short hh, ll; tsplit(xs[e], hh, ll);
          Bh[n * LDR + kx] = hh; Bl[n * LDR + kx] = ll;
        }
      } else {
        #pragma unroll
        for (int e = 0; e < 4; ++e){
          int n = sbn + g * 4 + e;
          Bh[n * LDR + kx] = qbh[g][e]; Bl[n * LDR + kx] = qbl[g][e];
        }
      }
    }
  };

  LOADT(0);
  STAGE(0);
  __syncthreads();

  for (int t = 0; t < NT; ++t){
    if (t + 1 < NT) LOADT(t + 1);
    short8 bh[4], bl[4];
    #pragma unroll
    for (int ct = 0; ct < 4; ++ct){
      int n = wn0 + ct * 16 + rowb;
      int idx = n * LDR + (kb ^ (((n >> 4) & 3) << 3));
      bh[ct] = *(const short8*)&Bh[idx];
      bl[ct] = *(const short8*)&Bl[idx];
    }
    #pragma unroll
    for (int rt = 0; rt < 4; ++rt){
      int r = wm0 + rt * 16 + rowb;
      int idx = r * LDR + (kb ^ (((r >> 3) & 3) << 3));
      short8 ah = *(const short8*)&Ah[idx];
      #pragma unroll
      for (int ct = 0; ct < 4; ++ct){
        acc[rt][ct] = __builtin_amdgcn_mfma_f32_16x16x32_bf16(ah, bh[ct], acc[rt][ct], 0, 0, 0);
        acc[rt][ct] = __builtin_amdgcn_mfma_f32_16x16x32_bf16(ah, bl[ct], acc[rt][ct], 0, 0, 0);
      }
      if constexpr (APRE==0){
        short8 al = *(const short8*)&Al[idx];
        #pragma unroll
        for (int ct = 0; ct < 4; ++ct)
          acc[rt][ct] = __builtin_amdgcn_mfma_f32_16x16x32_bf16(al, bh[ct], acc[rt][ct], 0, 0, 0);
      }
    }
    if (t + 1 < NT){
      __syncthreads();
      STAGE(t + 1);
      __syncthreads();
    }
  }

  #pragma unroll
  for (int ct = 0; ct < 4; ++ct){
    int gc = n0 + wn0 + ct * 16 + rowb;
    float bv = bias[gc];
    #pragma unroll
    for (int rt = 0; rt < 4; ++rt){
      int gr0 = m0 + wm0 + rt * 16 + (lane >> 4) * 4;
      #pragma unroll
      for (int q = 0; q < 4; ++q){
        size_t off = (size_t)(gr0 + q) * N + gc;
        float v = acc[rt][ct][q] + bv;
        if constexpr (EPI == 1) v = fmaxf(v, 0.f);
        if constexpr (EPI == 2) v += resid[off];
        if constexpr (EPI == 3) outb[off] = f2bf(fmaxf(v, 0.f));
        else                    outf[off] = v;
      }
    }
  }
}

// ---------------------------------------------------------------- attention v7 (MFMA flash)
// Round-12 changes vs v6: K-lo plane DROPPED (2-term QK: kh*qh + kh*ql;
// K-rounding error ~1e-3 on O(0.3) scores -> ~1e-4/layer in z, >>10x inside
// budget). LDS 113->73 KB -> 2 blocks/CU; 512-thread blocks (8 waves x 16
// q-rows = 128 rows), grid (8,8,8)=512 blocks -> cross-block staging/barrier
// overlap. Targets: q>=512 <=> qc>=4. Frag layouts HW-verified rounds 7-11.
__global__ __launch_bounds__(512) void attn_v7(
    const float* __restrict__ qkv, float* __restrict__ o)
{
  constexpr int LDK = 40;
  constexpr int LDV = 520;
  __shared__ unsigned short Khi[512*LDK];   // 40 KB
  __shared__ unsigned short Vt[32*LDV];     // 32.5 KB
  __shared__ float cbuf[8][16];

  const int tid = threadIdx.x;
  const int qc = blockIdx.x, h = blockIdx.y, b = blockIdx.z;
  const float* base = qkv + (size_t)b*1024*768;
  const int hoff = h*32;
  const float sc = 0.17677669529663687f;

  #pragma unroll
  for (int t = 0; t < 8; ++t){
    int i = tid + t*512;
    int row = i >> 3, c4 = (i & 7) * 4;
    float4 kv = *(const float4*)&base[(size_t)row*768 + 256 + hoff + c4];
    float ks[4] = {kv.x, kv.y, kv.z, kv.w};
    u16x4 hk;
    #pragma unroll
    for (int e = 0; e < 4; ++e) hk[e] = f2bf(ks[e]);
    *(u16x4*)&Khi[row*LDK + c4] = hk;
    float4 vv = *(const float4*)&base[(size_t)row*768 + 512 + hoff + c4];
    float vs[4] = {vv.x, vv.y, vv.z, vv.w};
    #pragma unroll
    for (int e = 0; e < 4; ++e)
      Vt[(c4 + e)*LDV + row] = f2bf(vs[e]);
  }

  const int wv = tid >> 6, lane = tid & 63;
  const int g = lane >> 4, r = lane & 15;
  const int q0w = qc*128 + wv*16;

  short8 qh, ql;
  {
    const float* qp = &base[(size_t)(q0w + r)*768 + hoff + g*8];
    float4 a = *(const float4*)qp;
    float4 c = *(const float4*)(qp + 4);
    float xs[8] = {a.x*sc, a.y*sc, a.z*sc, a.w*sc, c.x*sc, c.y*sc, c.z*sc, c.w*sc};
    #pragma unroll
    for (int e = 0; e < 8; ++e){
      unsigned short hb_ = f2bf(xs[e]);
      qh[e] = (short)hb_;
      ql[e] = (short)f2bf(xs[e] - bf2f(hb_));
    }
  }
  __syncthreads();

  float m = -1e30f, l = 0.f;
  f32x4 O0 = {0.f,0.f,0.f,0.f}, O1 = {0.f,0.f,0.f,0.f};

  for (int st = 0; st < 16; ++st){
    int key0 = st*32 + (r >> 2)*8 + (r & 3);
    short8 ah0 = *(const short8*)&Khi[key0*LDK + g*8];
    short8 ah1 = *(const short8*)&Khi[(key0+4)*LDK + g*8];
    f32x4 s0 = {0.f,0.f,0.f,0.f}, s1 = {0.f,0.f,0.f,0.f};
    s0 = __builtin_amdgcn_mfma_f32_16x16x32_bf16(ah0, qh, s0, 0,0,0);
    s0 = __builtin_amdgcn_mfma_f32_16x16x32_bf16(ah0, ql, s0, 0,0,0);
    s1 = __builtin_amdgcn_mfma_f32_16x16x32_bf16(ah1, qh, s1, 0,0,0);
    s1 = __builtin_amdgcn_mfma_f32_16x16x32_bf16(ah1, ql, s1, 0,0,0);
    float pv[8] = {s0[0],s0[1],s0[2],s0[3], s1[0],s1[1],s1[2],s1[3]};
    float tm = pv[0];
    #pragma unroll
    for (int j = 1; j < 8; ++j) tm = fmaxf(tm, pv[j]);
    tm = fmaxf(tm, __shfl_xor(tm, 16));
    tm = fmaxf(tm, __shfl_xor(tm, 32));
    float mn = fmaxf(m, tm);
    float ts = 0.f;
    #pragma unroll
    for (int j = 0; j < 8; ++j){ pv[j] = __expf(pv[j] - mn); ts += pv[j]; }
    ts += __shfl_xor(ts, 16);
    ts += __shfl_xor(ts, 32);
    if (__any(mn > m)){
      float corr = __expf(m - mn);
      if (lane < 16) cbuf[wv][lane] = corr;
      asm volatile("s_waitcnt lgkmcnt(0)" ::: "memory");
      f32x4 cf = *(const f32x4*)&cbuf[wv][g*4];
      #pragma unroll
      for (int j = 0; j < 4; ++j){ O0[j] *= cf[j]; O1[j] *= cf[j]; }
      l *= corr;
      m = mn;
    }
    l += ts;
    short8 pa;
    #pragma unroll
    for (int j = 0; j < 8; ++j) pa[j] = (short)f2bf(pv[j]);
    short8 v0 = *(const short8*)&Vt[(size_t)r*LDV + st*32 + g*8];
    short8 v1 = *(const short8*)&Vt[(size_t)(r+16)*LDV + st*32 + g*8];
    O0 = __builtin_amdgcn_mfma_f32_16x16x32_bf16(pa, v0, O0, 0,0,0);
    O1 = __builtin_amdgcn_mfma_f32_16x16x32_bf16(pa, v1, O1, 0,0,0);
  }

  // ---- self-attend tile (targets only): diagonal-masked, K/V from global
  if (qc >= 4){
    const float* kp = &base[(size_t)(q0w + r)*768 + 256 + hoff + g*8];
    float4 a = *(const float4*)kp;
    float4 c = *(const float4*)(kp + 4);
    float xs[8] = {a.x, a.y, a.z, a.w, c.x, c.y, c.z, c.w};
    short8 kh8;
    #pragma unroll
    for (int e = 0; e < 8; ++e) kh8[e] = (short)f2bf(xs[e]);
    f32x4 s = {0.f,0.f,0.f,0.f};
    s = __builtin_amdgcn_mfma_f32_16x16x32_bf16(kh8, qh, s, 0,0,0);
    s = __builtin_amdgcn_mfma_f32_16x16x32_bf16(kh8, ql, s, 0,0,0);
    float pv[8] = {0.f,0.f,0.f,0.f,0.f,0.f,0.f,0.f};
    float tm = -1e30f;
    #pragma unroll
    for (int j = 0; j < 4; ++j){
      bool al_ = (g*4 + j) == r;
      tm = fmaxf(tm, al_ ? s[j] : -1e30f);
    }
    tm = fmaxf(tm, __shfl_xor(tm, 16));
    tm = fmaxf(tm, __shfl_xor(tm, 32));
    float mn = fmaxf(m, tm);
    float ts = 0.f;
    #pragma unroll
    for (int j = 0; j < 4; ++j){
      bool al_ = (g*4 + j) == r;
      pv[j] = al_ ? __expf(s[j] - mn) : 0.f;
      ts += pv[j];
    }
    ts += __shfl_xor(ts, 16);
    ts += __shfl_xor(ts, 32);
    if (__any(mn > m)){
      float corr = __expf(m - mn);
      if (lane < 16) cbuf[wv][lane] = corr;
      asm volatile("s_waitcnt lgkmcnt(0)" ::: "memory");
      f32x4 cf = *(const f32x4*)&cbuf[wv][g*4];
      #pragma unroll
      for (int j = 0; j < 4; ++j){ O0[j] *= cf[j]; O1[j] *= cf[j]; }
      l *= corr;
      m = mn;
    }
    l += ts;
    short8 pa, v0, v1;
    #pragma unroll
    for (int j = 0; j < 8; ++j) pa[j] = (short)f2bf(pv[j]);
    #pragma unroll
    for (int j = 0; j < 4; ++j){
      const float* vp = &base[(size_t)(q0w + g*4 + j)*768 + 512 + hoff];
      v0[j] = (short)f2bf(vp[r]);
      v1[j] = (short)f2bf(vp[r + 16]);
      v0[j+4] = 0; v1[j+4] = 0;
    }
    O0 = __builtin_amdgcn_mfma_f32_16x16x32_bf16(pa, v0, O0, 0,0,0);
    O1 = __builtin_amdgcn_mfma_f32_16x16x32_bf16(pa, v1, O1, 0,0,0);
  }

  float inv = 1.f / l;
  if (lane < 16) cbuf[wv][lane] = inv;
  asm volatile("s_waitcnt lgkmcnt(0)" ::: "memory");
  f32x4 iv = *(const f32x4*)&cbuf[wv][g*4];
  float* op = o + ((size_t)b*1024 + q0w + g*4)*256 + hoff;
  #pragma unroll
  for (int j = 0; j < 4; ++j){
    op[(size_t)j*256 + r]      = O0[j] * iv[j];
    op[(size_t)j*256 + r + 16] = O1[j] * iv[j];
  }
}

// ---------------------------------------------------------------- launch
extern "C" void kernel_launch(void* const* d_in, const int* in_sizes, int n_in,
                              void* d_out, int out_size, void* d_ws, size_t ws_size,
                              hipStream_t stream)
{
  (void)in_sizes; (void)n_in; (void)out_size;
  const float* xc   = (const float*)d_in[0];
  const float* yc   = (const float*)d_in[1];
  const float* xt   = (const float*)d_in[2];
  const float* eW1  = (const float*)d_in[3];
  const float* eb1  = (const float*)d_in[4];
  const float* eW2  = (const float*)d_in[5];
  const float* eb2  = (const float*)d_in[6];
  const float* Wqkv = (const float*)d_in[7];
  const float* bqkv = (const float*)d_in[8];
  const float* Wo   = (const float*)d_in[9];
  const float* bo   = (const float*)d_in[10];
  const float* ln1g = (const float*)d_in[11];
  const float* ln1b = (const float*)d_in[12];
  const float* ln2g = (const float*)d_in[13];
  const float* ln2b = (const float*)d_in[14];
  const float* Wff1 = (const float*)d_in[15];
  const float* bff1 = (const float*)d_in[16];
  const float* Wff2 = (const float*)d_in[17];
  const float* bff2 = (const float*)d_in[18];

  float* zf = (float*)d_out;            // residual stream [8][1024][256] f32 = 8 MB
  char* ws = (char*)d_ws;
  float* hb      = (float*)(ws);                        // 8 MiB (attn out / enc hid)
  float* scratch = (float*)(ws + (size_t)8*1024*1024);  // qkv f32 (24 MiB) / ffh bf16 (16 MiB)

  const size_t MiB = 1024*1024;
  const bool hugews = (ws_size == 0) || (ws_size >= 64*MiB);   // fill counters show ws = 256 MiB
  const bool bigws  = (ws_size == 0) || (ws_size >= 33*MiB);

  if (hugews){
    // persistent split planes at ws+32MiB (~18.3 MiB) + LN stats at ws+52MiB
    unsigned short* W = (unsigned short*)(ws + 32*MiB);
    unsigned short* qkvh_a = W;                 // 6*196608
    unsigned short* qkvl_a = W + 1179648;
    unsigned short* woh_a  = W + 2359296;       // 6*65536
    unsigned short* wol_a  = W + 2752512;
    unsigned short* w1h_a  = W + 3145728;       // 6*262144
    unsigned short* w1l_a  = W + 4718592;
    unsigned short* w2h_a  = W + 6291456;
    unsigned short* w2l_a  = W + 7864320;
    unsigned short* e2h    = W + 9437184;       // 65536
    unsigned short* e2l    = W + 9502720;
    float2* st1 = (float2*)(ws + 52*MiB);       // 8192 float2 = 64 KB
    float2* st2 = st1 + 8192;
    unsigned short* ffh_b  = (unsigned short*)scratch;   // 16 MiB, after attn

    conv2<<<1536, 256, 0, stream>>>((const float4*)Wqkv, 294912, (u16x4*)qkvh_a, (u16x4*)qkvl_a,
                                    (const float4*)Wo,    98304, (u16x4*)woh_a,  (u16x4*)wol_a);
    conv2<<<3072, 256, 0, stream>>>((const float4*)Wff1, 393216, (u16x4*)w1h_a, (u16x4*)w1l_a,
                                    (const float4*)Wff2, 393216, (u16x4*)w2h_a, (u16x4*)w2l_a);
    conv2<<<64, 256, 0, stream>>>((const float4*)eW2, 16384, (u16x4*)e2h, (u16x4*)e2l,
                                  nullptr, 0, nullptr, nullptr);

    encoder_s1<<<8192, 256, 0, stream>>>(xc, yc, xt, eW1, eb1, hb);
    gemm_mfma<0,1,0,0><<<dim3(2,64), 256, 0, stream>>>(hb, nullptr, nullptr, e2h, e2l,
                                                       nullptr, nullptr, nullptr, eb2, nullptr, zf, nullptr, 256, 256);

    for (int l=0; l<6; l++){
      unsigned short* qkvh = qkvh_a + (size_t)l*196608;
      unsigned short* qkvl = qkvl_a + (size_t)l*196608;
      unsigned short* woh  = woh_a  + (size_t)l*65536;
      unsigned short* wol  = wol_a  + (size_t)l*65536;
      unsigned short* w1h  = w1h_a  + (size_t)l*262144;
      unsigned short* w1l  = w1l_a  + (size_t)l*262144;
      unsigned short* w2h  = w2h_a  + (size_t)l*262144;
      unsigned short* w2l  = w2l_a  + (size_t)l*262144;

      ln_stats<<<2048, 256, 0, stream>>>(zf, st1);
      gemm_mfma<0,1,0,1><<<dim3(6,64), 256, 0, stream>>>(zf, nullptr, nullptr, qkvh, qkvl,
                                                         st1, ln1g+l*256, ln1b+l*256,
                                                         bqkv+l*768, nullptr, scratch, nullptr, 768, 256);
      attn_v7<<<dim3(8,8,8), 512, 0, stream>>>(scratch, hb);
      gemm_mfma<0,1,2,0><<<dim3(2,64), 256, 0, stream>>>(hb, nullptr, nullptr, woh, wol,
                                                         nullptr, nullptr, nullptr, bo+l*256, zf, zf, nullptr, 256, 256);
      ln_stats<<<2048, 256, 0, stream>>>(zf, st2);
      gemm_mfma<0,1,3,1><<<dim3(8,64), 256, 0, stream>>>(zf, nullptr, nullptr, w1h, w1l,
                                                         st2, ln2g+l*256, ln2b+l*256,
                                                         bff1+l*1024, nullptr, nullptr, ffh_b, 1024, 256);
      gemm_mfma<1,1,2,0><<<dim3(2,64), 256, 0, stream>>>(nullptr, ffh_b, nullptr, w2h, w2l,
                                                         nullptr, nullptr, nullptr, bff2+l*256, zf, zf, nullptr, 256, 1024);
    }
  } else if (bigws){
    // round-10 layout: per-layer conv + separate ln_v2 (LNA=0 everywhere)
    unsigned short* wsA = (unsigned short*)(ws + 32*MiB);
    unsigned short* wsB = (unsigned short*)(ws + 24*MiB);
    unsigned short* qkvh = wsA,            * qkvl = wsA + 196608;
    unsigned short* woh  = wsA + 393216,   * wol  = wsA + 458752;
    unsigned short* w1h  = wsB,            * w1l  = wsB + 262144;
    unsigned short* w2h  = wsB + 524288,   * w2l  = wsB + 786432;
    unsigned short* ffh_b = (unsigned short*)scratch;

    conv2<<<64, 256, 0, stream>>>((const float4*)eW2, 16384, (u16x4*)wsA, (u16x4*)(wsA+65536),
                                  nullptr, 0, nullptr, nullptr);
    encoder_s1<<<8192, 256, 0, stream>>>(xc, yc, xt, eW1, eb1, hb);
    gemm_mfma<0,1,0,0><<<dim3(2,64), 256, 0, stream>>>(hb, nullptr, nullptr, wsA, wsA+65536,
                                                       nullptr, nullptr, nullptr, eb2, nullptr, zf, nullptr, 256, 256);
    for (int l=0; l<6; l++){
      const float* Wq = Wqkv + (size_t)l*256*768;
      const float* Wl = Wo   + (size_t)l*256*256;
      const float* W1 = Wff1 + (size_t)l*256*1024;
      const float* W2 = Wff2 + (size_t)l*1024*256;

      conv2<<<256, 256, 0, stream>>>((const float4*)Wq, 49152, (u16x4*)qkvh, (u16x4*)qkvl,
                                     (const float4*)Wl, 16384, (u16x4*)woh,  (u16x4*)wol);
      ln_v2<<<2048, 256, 0, stream>>>(zf, ln1g+l*256, ln1b+l*256, hb);
      gemm_mfma<0,1,0,0><<<dim3(6,64), 256, 0, stream>>>(hb, nullptr, nullptr, qkvh, qkvl,
                                                         nullptr, nullptr, nullptr,
                                                         bqkv+l*768, nullptr, scratch, nullptr, 768, 256);
      attn_v7<<<dim3(8,8,8), 512, 0, stream>>>(scratch, hb);
      conv2<<<512, 256, 0, stream>>>((const float4*)W1, 65536, (u16x4*)w1h, (u16x4*)w1l,
                                     (const float4*)W2, 65536, (u16x4*)w2h, (u16x4*)w2l);
      gemm_mfma<0,1,2,0><<<dim3(2,64), 256, 0, stream>>>(hb, nullptr, nullptr, woh, wol,
                                                         nullptr, nullptr, nullptr, bo+l*256, zf, zf, nullptr, 256, 256);
      ln_v2<<<2048, 256, 0, stream>>>(zf, ln2g+l*256, ln2b+l*256, hb);
      gemm_mfma<0,1,3,0><<<dim3(8,64), 256, 0, stream>>>(hb, nullptr, nullptr, w1h, w1l,
                                                         nullptr, nullptr, nullptr,
                                                         bff1+l*1024, nullptr, nullptr, ffh_b, 1024, 256);
      gemm_mfma<1,1,2,0><<<dim3(2,64), 256, 0, stream>>>(nullptr, ffh_b, nullptr, w2h, w2l,
                                                         nullptr, nullptr, nullptr, bff2+l*256, zf, zf, nullptr, 256, 1024);
    }
  } else {
    // minimal-ws fallback: in-kernel conversion + separate LN, chunked scratch
    encoder_s1<<<8192, 256, 0, stream>>>(xc, yc, xt, eW1, eb1, hb);
    gemm_mfma<0,0,0,0><<<dim3(2,64), 256, 0, stream>>>(hb, nullptr, eW2, nullptr, nullptr,
                                                       nullptr, nullptr, nullptr, eb2, nullptr, zf, nullptr, 256, 256);
    for (int l=0; l<6; l++){
      const float* Wq = Wqkv + (size_t)l*256*768;
      const float* Wl = Wo   + (size_t)l*256*256;
      const float* W1 = Wff1 + (size_t)l*256*1024;
      const float* W2 = Wff2 + (size_t)l*1024*256;

      ln_v2<<<2048, 256, 0, stream>>>(zf, ln1g+l*256, ln1b+l*256, hb);
      for (int c=0; c<4; c++){
        float* hrows = hb + (size_t)c*2048*256;
        gemm_mfma<0,0,0,0><<<dim3(6,16), 256, 0, stream>>>(hrows, nullptr, Wq, nullptr, nullptr,
                                                           nullptr, nullptr, nullptr,
                                                           bqkv+l*768, nullptr, scratch, nullptr, 768, 256);
        attn_v7<<<dim3(8,8,2), 512, 0, stream>>>(scratch, hrows);
      }
      gemm_mfma<0,0,2,0><<<dim3(2,64), 256, 0, stream>>>(hb, nullptr, Wl, nullptr, nullptr,
                                                         nullptr, nullptr, nullptr, bo+l*256, zf, zf, nullptr, 256, 256);
      ln_v2<<<2048, 256, 0, stream>>>(zf, ln2g+l*256, ln2b+l*256, hb);
      for (int c=0; c<4; c++){
        float* hrows = hb + (size_t)c*2048*256;
        float* zrows = zf + (size_t)c*2048*256;
        gemm_mfma<0,0,1,0><<<dim3(8,16), 256, 0, stream>>>(hrows, nullptr, W1, nullptr, nullptr,
                                                           nullptr, nullptr, nullptr,
                                                           bff1+l*1024, nullptr, scratch, nullptr, 1024, 256);
        gemm_mfma<0,0,2,0><<<dim3(2,16), 256, 0, stream>>>(scratch, nullptr, W2, nullptr, nullptr,
                                                           nullptr, nullptr, nullptr,
                                                           bff2+l*256, zrows, zrows, nullptr, 256, 1024);
      }
    }
  }
}